// Round 13
// baseline (256.000 us; speedup 1.0000x reference)
//
#include <hip/hip_runtime.h>
#include <stdint.h>

// VectorQuantization: out[n] = codebook[argmax_k dot(x[n], codebook[k])]
// (argmax invariant to positive per-row scaling -> L2-normalize skipped,
//  and per-row max-norm int8 quantization is equally argmax-preserving)
//
// R16 = R15 + A-operand direct from L2 (B keeps the proven LDS path).
// Pipe budget at R15 (per kt ~3675 cyc/CU): MFMA 28% + VALU 40% + LDS ~31%
// ~= 99% packed -> must REMOVE pipe work. A's LDS round-trip is pure
// overhead: A-tile is 16 KB/kt, L2-resident, fragment addresses static.
// Per kt now: 4 A global loads (current kt) -> stageB(kt+1) (2 gll) ->
// 8 B ds_reads -> MFMA (compiler's auto vmcnt(2) waits A only, B stages
// stay in flight) -> fold -> vmcnt(0)+barrier (B stages, ledger unchanged).
// Deletes per kt: 2 gll16, 16 KB LDS writes, 4/12 ds_reads (LDS pipe -33%);
// zero new registers (A_ was already a 16-reg destination).
// A global layout: lane reads row row0+wm*64+i*16+l15, bytes
// (kt&7)*64+quad*16 == the unswizzled logical chunk the old XOR-swizzled
// LDS path reconstructed (verified against the 16x16x64 A fragment map).
//
// Race ledger (B-only staging, 1 barrier/kt): during kt, ds_reads hit buf
// kt&1 only. stageB(kt+1) (top of kt) targets buf (kt+1)&1 whose last
// readers ran during kt-1, strictly before the kt-1 -> kt barrier.
// vmcnt(0) before the end-of-kt barrier drains this wave's B stages (A
// loads already drained by the compiler's pre-MFMA waitcnt); barrier
// globalizes. Unit seam: prologue stageB(0) + vmcnt(0) + barrier precedes
// any read; u-1's last buf0 reads were pre-barrier at its kt=G-2 -> safe.
//
// Carried from R15: tournament fold (top-2-of-4 + top2-union, tree ILP),
// 2-unit loop (256 blocks x 2), i8 MFMA 16x16x64, per-row x absmax +
// global cb absmax quant (argmax-invariant), MARGIN_I=8000 (~29 sigma) +
// exact-fp64 recheck, zero-bank-conflict XOR swizzle on B staging,
// packed int top-2 keys, ballot winner-lane recovery, 4-launch structure.
//
// Session ledger (vq dispatch / total, us): R3 fp16 222/308 | R8 i8
// 100.5/230 | R10 101.3/229.9 | R13 fold-chain 111.4/217.7 (REGR) |
// R14 100.7/219.9 | R15 98.1/218.0 | R16: this.
// Failed: R6 lambda-ref spill, R9 launch-bounds spill, R11 reg-direct
// 1-wave, R12 cooperative fusion.

typedef int i32x4 __attribute__((ext_vector_type(4)));

#define M_ROWS 8192
#define DIM 512
#define DIMB 512                      /* bytes per i8 row */
#define K_CODES 16384
#define BM 256
#define BN 256
#define BKB 64                        /* K-tile depth in elements == bytes */
#define NSPLIT 16
#define NT ((K_CODES / NSPLIT) / BN)  /* 4 col-tiles per unit */
#define KT_CT (DIM / BKB)             /* 8 K-tiles per col-tile */
#define G (NT * KT_CT)                /* 32 K-tiles per unit */
#define MARGIN_I 8000.0f
#define INT_MIN_K (-2147483647 - 1)

typedef __attribute__((address_space(1))) uint32_t as1_u32;
typedef __attribute__((address_space(3))) uint32_t as3_u32;

__device__ __forceinline__ void gll16(const void* g, void* l) {
  // async global->LDS, 16B/lane; LDS dest = wave-uniform base + lane*16
  __builtin_amdgcn_global_load_lds((const as1_u32*)(uintptr_t)g,
                                   (as3_u32*)(uintptr_t)l, 16, 0, 0);
}

__device__ __forceinline__ float absmax4(float4 v) {
  return fmaxf(fmaxf(fabsf(v.x), fabsf(v.y)), fmaxf(fabsf(v.z), fabsf(v.w)));
}

__device__ __forceinline__ unsigned pack4(float a, float b, float c, float d, float inv) {
  const int q0 = __float2int_rn(a * inv), q1 = __float2int_rn(b * inv);
  const int q2 = __float2int_rn(c * inv), q3 = __float2int_rn(d * inv);
  return (unsigned)(q0 & 255) | ((unsigned)(q1 & 255) << 8) |
         ((unsigned)(q2 & 255) << 16) | ((unsigned)(q3 & 255) << 24);
}

// blocks [0,1024): one wave per x row -> per-row absmax quantize to i8.
// blocks [1024,2048): grid-stride absmax over codebook -> pmax[bid-1024]
// (plain store; cb_quant reduces the partials -> no atomic, no memset).
__global__ __launch_bounds__(512) void prep(
    const float* __restrict__ x, const float* __restrict__ cb,
    signed char* __restrict__ xq, float* __restrict__ pmax) {
  __shared__ float sm[8];
  if (blockIdx.x < 1024) {
    const int wv = threadIdx.x >> 6, lane = threadIdx.x & 63;
    const int row = blockIdx.x * 8 + wv;
    const float* xr = x + (size_t)row * DIM + lane * 8;
    const float4 v0 = *(const float4*)xr;
    const float4 v1 = *(const float4*)(xr + 4);
    float m = fmaxf(absmax4(v0), absmax4(v1));
#pragma unroll
    for (int d = 1; d < 64; d <<= 1) m = fmaxf(m, __shfl_xor(m, d));
    const float inv = m > 0.f ? 127.0f / m : 0.f;
    uint2 u;
    u.x = pack4(v0.x, v0.y, v0.z, v0.w, inv);
    u.y = pack4(v1.x, v1.y, v1.z, v1.w, inv);
    ((uint2*)(xq + (size_t)row * DIMB))[lane] = u;
  } else {
    const int n4 = K_CODES * DIM / 4;
    float m = 0.f;
    for (int i = (blockIdx.x - 1024) * 512 + threadIdx.x; i < n4; i += 512 * 1024)
      m = fmaxf(m, absmax4(((const float4*)cb)[i]));
#pragma unroll
    for (int d = 1; d < 64; d <<= 1) m = fmaxf(m, __shfl_xor(m, d));
    if ((threadIdx.x & 63) == 0) sm[threadIdx.x >> 6] = m;
    __syncthreads();
    if (threadIdx.x == 0) {
#pragma unroll
      for (int i = 1; i < 8; ++i) m = fmaxf(m, sm[i]);
      pmax[blockIdx.x - 1024] = m;
    }
  }
}

__global__ __launch_bounds__(256) void cb_quant(
    const float* __restrict__ cb, signed char* __restrict__ cq,
    const float* __restrict__ pmax) {
  __shared__ float sm[4];
  float m = 0.f;
#pragma unroll
  for (int q = 0; q < 4; ++q) m = fmaxf(m, pmax[q * 256 + threadIdx.x]);
#pragma unroll
  for (int d = 1; d < 64; d <<= 1) m = fmaxf(m, __shfl_xor(m, d));
  if ((threadIdx.x & 63) == 0) sm[threadIdx.x >> 6] = m;
  __syncthreads();
  const float mx = fmaxf(fmaxf(sm[0], sm[1]), fmaxf(sm[2], sm[3]));
  const float inv = mx > 0.f ? 127.0f / mx : 0.f;
  const size_t t = (size_t)blockIdx.x * 256 + threadIdx.x;  // 8 elems/thread
  const float* src = cb + t * 8;
  const float4 v0 = *(const float4*)src;
  const float4 v1 = *(const float4*)(src + 4);
  uint2 u;
  u.x = pack4(v0.x, v0.y, v0.z, v0.w, inv);
  u.y = pack4(v1.x, v1.y, v1.z, v1.w, inv);
  ((uint2*)cq)[t] = u;
}

__global__ __launch_bounds__(512, 2) void vq_argmax(
    const signed char* __restrict__ xq, const signed char* __restrict__ cq,
    float* __restrict__ pv, int* __restrict__ pi) {
  // B-only staging: 2 rotating K-tile buffers x (256 rows x 64B) = 32 KiB
  __shared__ signed char lds[2][BN * BKB];

  const int tid = threadIdx.x;
  const int lane = tid & 63;
  const int w = tid >> 6;
  const int wm = w >> 1, wn = w & 1;       // 4M x 2N wave grid
  const int l15 = lane & 15, quad = lane >> 4;
  // B fragment: swizzled 16B-chunk byte offset (XOR chunk swizzle, as before)
  const int kq = ((quad ^ ((l15 >> 1) & 3)) << 4);
  const int boff = (wn * 128 + l15) * BKB + kq;

  // B staging map: slot s = r*512+tid holds chunk (row=s>>2, kc=(s&3)^((row>>1)&3))
  int eoff0, eoff1, doff0, doff1;
  {
    const int s1 = 512 + tid;
    const int r0 = tid >> 2, r1 = s1 >> 2;
    eoff0 = r0 * DIMB + (((tid & 3) ^ ((r0 >> 1) & 3)) << 4);
    eoff1 = r1 * DIMB + (((s1 & 3) ^ ((r1 >> 1) & 3)) << 4);
    doff0 = (tid & 448) << 4;
    doff1 = (512 + (tid & 448)) << 4;
  }

  // 2 (rb,split) units per block: 256 blocks x 2 = 512 units
#pragma unroll 1
  for (int u = 0; u < 2; ++u) {
    const int unit = u * 256 + blockIdx.x;
    const int rb = unit & 31;
    const int split = unit >> 5;
    const int row0 = rb * BM;
    // A direct from L2: this lane's A-row base (row = row0+wm*64+i*16+l15,
    // byte = kt_in_coltile*64 + quad*16); frag i offset = i*16*DIMB
    const signed char* Arow =
        xq + (size_t)(row0 + wm * 64 + l15) * DIMB + quad * 16;
    const signed char* Bsrc = cq + (size_t)split * (K_CODES / NSPLIT) * DIMB;

    auto stageB = [&](int t) {
      const signed char* g = Bsrc + (size_t)(t >> 3) * (BN * DIMB) + (t & 7) * BKB;
      signed char* l = &lds[t & 1][0];
      gll16(g + eoff0, l + doff0);
      gll16(g + eoff1, l + doff1);
    };

    // packed top-2 int keys per (i,r) row-slot: key = (D<<5) | icode_inv
    int K1[4][4], K2[4][4];
#pragma unroll
    for (int i = 0; i < 4; ++i)
#pragma unroll
      for (int r = 0; r < 4; ++r) { K1[i][r] = INT_MIN_K; K2[i][r] = INT_MIN_K; }

    i32x4 acc[4][8];

    // tournament fold over one j-half (4 cols): top-2-of-4 max/min tree +
    // top2-union merge. Keys unique (codes) -> ties impossible -> exact.
    auto fold = [&](int j0, int kt) {
      const int icb = 31 - (kt >> 3) * 8;   // icode_inv = icb - j
#pragma unroll
      for (int i = 0; i < 4; ++i)
#pragma unroll
        for (int r = 0; r < 4; ++r) {
          const int k0 = (int)(((unsigned)acc[i][j0 + 0][r] << 5) | (unsigned)(icb - j0 - 0));
          const int k1 = (int)(((unsigned)acc[i][j0 + 1][r] << 5) | (unsigned)(icb - j0 - 1));
          const int k2 = (int)(((unsigned)acc[i][j0 + 2][r] << 5) | (unsigned)(icb - j0 - 2));
          const int k3 = (int)(((unsigned)acc[i][j0 + 3][r] << 5) | (unsigned)(icb - j0 - 3));
          const int h01 = k0 > k1 ? k0 : k1, l01 = k0 > k1 ? k1 : k0;
          const int h23 = k2 > k3 ? k2 : k3, l23 = k2 > k3 ? k3 : k2;
          const int m1 = h01 > h23 ? h01 : h23;
          const int lw = h01 > h23 ? l01 : l23;   // lo of winning pair
          const int lo2 = h01 > h23 ? h23 : h01;  // losing pair's hi
          const int m2 = lw > lo2 ? lw : lo2;     // second of the 4
          const int s = K1[i][r] > m1 ? m1 : K1[i][r];
          const int other = K1[i][r] > m1 ? K2[i][r] : m2;
          K1[i][r] = K1[i][r] > m1 ? K1[i][r] : m1;
          K2[i][r] = s > other ? s : other;
        }
    };

    // prologue: stage B K-tile 0, drain, sync (also the unit seam barrier)
    stageB(0);
    asm volatile("s_waitcnt vmcnt(0)" ::: "memory");
    __builtin_amdgcn_s_barrier();
    asm volatile("" ::: "memory");

#pragma unroll 1
    for (int kt = 0; kt < G; ++kt) {
      const int bk = kt & 1;
      // A global loads for CURRENT kt first (L2 ~200-400 cyc, consumed after
      // the B reads -> compiler's auto vmcnt(2) covers them, B stages stay
      // in flight); then stage B(kt+1) for max lead time
      i32x4 A_[4];
      {
        const signed char* ap = Arow + (kt & 7) * BKB;
#pragma unroll
        for (int i = 0; i < 4; ++i)
          A_[i] = *(const i32x4*)(ap + (size_t)i * (16 * DIMB));
      }
      if (kt + 1 < G) stageB(kt + 1);

      if ((kt & 7) == 0) {
#pragma unroll
        for (int i = 0; i < 4; ++i)
#pragma unroll
          for (int j = 0; j < 8; ++j) acc[i][j] = (i32x4){0, 0, 0, 0};
      }
      const signed char* Bb = &lds[bk][0];

      // 8 B fragment ds_reads up front; counted lgkm lets the later reads
      // complete under the first MFMA group
      i32x4 B_[8];
#pragma unroll
      for (int j = 0; j < 8; ++j) B_[j] = *(const i32x4*)&Bb[boff + j * (16 * BKB)];

      __builtin_amdgcn_s_setprio(1);
#pragma unroll
      for (int j = 0; j < 4; ++j)
#pragma unroll
        for (int i = 0; i < 4; ++i)
          acc[i][j] = __builtin_amdgcn_mfma_i32_16x16x64_i8(A_[i], B_[j], acc[i][j], 0, 0, 0);
      __builtin_amdgcn_s_setprio(0);
      if ((kt & 7) == 7) fold(0, kt);   // VALU half-fold under next MFMA group
      __builtin_amdgcn_s_setprio(1);
#pragma unroll
      for (int j = 4; j < 8; ++j)
#pragma unroll
        for (int i = 0; i < 4; ++i)
          acc[i][j] = __builtin_amdgcn_mfma_i32_16x16x64_i8(A_[i], B_[j], acc[i][j], 0, 0, 0);
      __builtin_amdgcn_s_setprio(0);
      if ((kt & 7) == 7) fold(4, kt);

      // drain this wave's B stages (A loads already waited), then globalize
      if (kt + 1 < G) {
        asm volatile("s_waitcnt vmcnt(0)" ::: "memory");
        __builtin_amdgcn_s_barrier();
        asm volatile("" ::: "memory");
      }
    }

    // butterfly-merge top-2 across the 16 column-lanes of each quad, recover
    // winner lane via ballot (first set bit = lowest l15 = lowest index on tie)
    const int nb = split * (K_CODES / NSPLIT);
#pragma unroll
    for (int i = 0; i < 4; ++i)
#pragma unroll
      for (int r = 0; r < 4; ++r) {
        const int p1 = K1[i][r], p2 = K2[i][r];
        int a1 = p1, a2 = p2;
#pragma unroll
        for (int d = 1; d < 16; d <<= 1) {
          const int b1 = __shfl_xor(a1, d);
          const int b2 = __shfl_xor(a2, d);
          const int hi = a1 > b1 ? a1 : b1;
          const int lo = a1 > b1 ? b1 : a1;
          const int mx = a2 > b2 ? a2 : b2;
          a1 = hi;
          a2 = lo > mx ? lo : mx;
        }
        const unsigned long long bl1 = __ballot(p1 == a1);
        const int s1 = __ffsll((unsigned long long)((bl1 >> (quad * 16)) & 0xFFFFull)) - 1;
        const unsigned long long bl2 = __ballot((p2 == a2) || (p1 == a2 && l15 != s1));
        const int s2 = __ffsll((unsigned long long)((bl2 >> (quad * 16)) & 0xFFFFull)) - 1;
        if (l15 == 0) {
          const int code1 = 31 - (a1 & 31);
          const int code2 = 31 - (a2 & 31);
          const int col1 = nb + (code1 >> 3) * BN + wn * 128 + (code1 & 7) * 16 + s1;
          const int col2 = nb + (code2 >> 3) * BN + wn * 128 + (code2 & 7) * 16 + s2;
          const int rl = wm * 64 + i * 16 + quad * 4 + r;
          const size_t o = (size_t)(row0 + rl) * 64 + (size_t)(split * 4 + wn * 2);
          pv[o] = (float)(a1 >> 5); pi[o] = col1;       // D in int units; margin
          pv[o + 1] = (float)(a2 >> 5); pi[o + 1] = col2;  // test is relative/row
        }
      }
  }
}

__global__ void recheck_gather(const float* __restrict__ pv, const int* __restrict__ pi,
                               const float* __restrict__ x, const float* __restrict__ cb,
                               float* __restrict__ out) {
  const int row = blockIdx.x;
  const int lane = threadIdx.x;   // 64 candidates = 16 splits x 2 halves x top-2
  float v = pv[(size_t)row * 64 + lane];
  int ci = pi[(size_t)row * 64 + lane];

  // wave max with lowest-index tie-break
  float m1 = v; int mi1 = ci;
#pragma unroll
  for (int d = 1; d < 64; d <<= 1) {
    float ov = __shfl_xor(m1, d);
    int oi = __shfl_xor(mi1, d);
    if (ov > m1 || (ov == m1 && oi < mi1)) { m1 = ov; mi1 = oi; }
  }

  const bool flag = (v >= m1 - MARGIN_I);
  const unsigned long long mask = __ballot(flag);
  int winner;
  if (__popcll(mask) == 1) {
    winner = mi1;   // approx winner is ~29-sigma clear of every other candidate
  } else {
    // exact fp64 dot from original fp32 inputs for each flagged candidate
    double e = -1.0e300;
    if (flag) {
      const float* xr = x + (size_t)row * DIM;
      const float* cr = cb + (size_t)ci * DIM;
      double s = 0.0;
#pragma unroll 4
      for (int t = 0; t < DIM; t += 4) {
        const float4 a = *(const float4*)(xr + t);
        const float4 b = *(const float4*)(cr + t);
        s += (double)a.x * b.x + (double)a.y * b.y + (double)a.z * b.z + (double)a.w * b.w;
      }
      e = s;
    }
    int ei = flag ? ci : 0x7fffffff;
#pragma unroll
    for (int d = 1; d < 64; d <<= 1) {
      double oe = __shfl_xor(e, d);
      int oi = __shfl_xor(ei, d);
      if (oe > e || (oe == e && oi < ei)) { e = oe; ei = oi; }
    }
    winner = ei;
  }

  const float4* src = (const float4*)(cb + (size_t)winner * DIM);
  float4* dst = (float4*)(out + (size_t)row * DIM);
  dst[lane] = src[lane];         // 512 f32 = 128 float4, 64 lanes x 2
  dst[lane + 64] = src[lane + 64];
}

extern "C" void kernel_launch(void* const* d_in, const int* in_sizes, int n_in,
                              void* d_out, int out_size, void* d_ws, size_t ws_size,
                              hipStream_t stream) {
  const float* x = (const float*)d_in[0];
  const float* cb = (const float*)d_in[1];
  float* out = (float*)d_out;

  // ws layout: xq(4MB) cq(8MB) pv(2MB) pi(2MB) pmax(4KB)
  signed char* xq = (signed char*)d_ws;
  signed char* cq = xq + (size_t)M_ROWS * DIMB;
  float* pv = (float*)(cq + (size_t)K_CODES * DIMB);
  int* pi = (int*)(pv + (size_t)M_ROWS * 64);
  float* pmax = (float*)(pi + (size_t)M_ROWS * 64);

  prep<<<2048, 512, 0, stream>>>(x, cb, xq, pmax);
  cb_quant<<<K_CODES * DIM / 8 / 256, 256, 0, stream>>>(cb, cq, pmax);
  vq_argmax<<<256, 512, 0, stream>>>(xq, cq, pv, pi);
  recheck_gather<<<M_ROWS, 64, 0, stream>>>(pv, pi, x, cb, out);
}

// Round 14
// 217.715 us; speedup vs baseline: 1.1758x; 1.1758x over previous
//
#include <hip/hip_runtime.h>
#include <stdint.h>

// VectorQuantization: out[n] = codebook[argmax_k dot(x[n], codebook[k])]
// (argmax invariant to positive per-row scaling -> L2-normalize skipped,
//  and per-row max-norm int8 quantization is equally argmax-preserving)
//
// R17 = R15 verbatim (best measured: vq 98.1 us, total 218.0). R16's
// A-direct-from-L2 regressed vq to 140 us: each A fragment global load had
// lanes on 16 different 512B-pitch rows -> 16 disjoint 64B segments per
// instruction (uncoalesced), flooding the VMEM request pipe (MfmaUtil
// 28->20, VALUBusy 40->28, both DOWN with time UP = stall-bound). The LDS
// staging path exists precisely to coalesce that pattern. Reverted.
//
// Final structure:
//  - i8 quantization: per-row absmax for x, single global absmax for cb
//    (both argmax-invariant; int-dot noise sigma ~276 int units).
//  - vq_argmax: 256x256 tile / 8 waves, 2 rotating B+A K-tile LDS buffers
//    (64 KiB), stage kt+1 at top of body (4x global_load_lds dwordx4,
//    zero-bank-conflict XOR chunk swizzle, SQ_LDS_BANK_CONFLICT == 0),
//    12 ds_read_b128 up front in need-order, 32 MFMA (i32_16x16x64_i8) in
//    two setprio(1) groups, tournament fold (top-2-of-4 + top2-union
//    merge; keys unique -> branchless max/min network exact) interleaved
//    between MFMA groups, vmcnt(0)+barrier per K-tile, 2 (rb,split) units
//    per block (256 blocks x 2 = 512 units).
//  - Race ledger: during kt, ds_reads hit buf kt&1 only. Stage of kt+1
//    (top of kt) targets buf (kt+1)&1 whose last readers ran during kt-1,
//    strictly before the kt-1 -> kt barrier. vmcnt(0) before the end-of-kt
//    barrier drains this wave's stages; barrier globalizes. Unit seam:
//    prologue stage+vmcnt(0)+barrier precedes any read -> safe.
//  - Top-2 per (row, split-half): packed int keys (D<<5 | inverted 5-bit
//    (coltile,j) code -> free lowest-index tie-break), 16-lane butterfly,
//    ballot winner-lane recovery.
//  - recheck_gather: wave max over 64 candidates/row; if any other
//    candidate within MARGIN_I=8000 (~29 sigma), exact fp64 dots from the
//    original fp32 inputs decide (lowest index on tie); gather winner row.
//  - 4 launches: prep (x-quant + cb absmax partials) -> cb_quant (reduce
//    partials + quantize) -> vq_argmax -> recheck_gather.
//
// Session ledger (vq dispatch / end-to-end total, us):
//   R3 fp16 3-pass: 222/308 | R8 i8: 100.5/230 | R10: 101.3/229.9 |
//   R13 fold-chain: 111.4/217.7 (vq regr) | R14: 100.7/219.9 |
//   R15: 98.1/218.0 (BEST) | R16 A-direct: 140.0/256.0 (regr) | R17: R15.
//   Failed structures: R6 lambda-ref spill, R9 launch-bounds spill,
//   R11 register-direct (1 wave/SIMD), R12 cooperative fusion (grid.sync).
//   Exhausted levers: 7 barrier schedules (+-11%), occupancy (240-reg
//   accumulator wall), operand-from-L2 (coalescing), 32x32 MFMA (key-state
//   regs), fold micro-opt (banked), launch count (banked). vq pipe budget
//   MFMA 28 + VALU 40 + LDS ~31 ~= 99% packed.

typedef int i32x4 __attribute__((ext_vector_type(4)));

#define M_ROWS 8192
#define DIM 512
#define DIMB 512                      /* bytes per i8 row */
#define K_CODES 16384
#define BM 256
#define BN 256
#define BKB 64                        /* K-tile depth in elements == bytes */
#define NSPLIT 16
#define NT ((K_CODES / NSPLIT) / BN)  /* 4 col-tiles per unit */
#define KT_CT (DIM / BKB)             /* 8 K-tiles per col-tile */
#define G (NT * KT_CT)                /* 32 K-tiles per unit */
#define MARGIN_I 8000.0f
#define INT_MIN_K (-2147483647 - 1)

typedef __attribute__((address_space(1))) uint32_t as1_u32;
typedef __attribute__((address_space(3))) uint32_t as3_u32;

__device__ __forceinline__ void gll16(const void* g, void* l) {
  // async global->LDS, 16B/lane; LDS dest = wave-uniform base + lane*16
  __builtin_amdgcn_global_load_lds((const as1_u32*)(uintptr_t)g,
                                   (as3_u32*)(uintptr_t)l, 16, 0, 0);
}

__device__ __forceinline__ float absmax4(float4 v) {
  return fmaxf(fmaxf(fabsf(v.x), fabsf(v.y)), fmaxf(fabsf(v.z), fabsf(v.w)));
}

__device__ __forceinline__ unsigned pack4(float a, float b, float c, float d, float inv) {
  const int q0 = __float2int_rn(a * inv), q1 = __float2int_rn(b * inv);
  const int q2 = __float2int_rn(c * inv), q3 = __float2int_rn(d * inv);
  return (unsigned)(q0 & 255) | ((unsigned)(q1 & 255) << 8) |
         ((unsigned)(q2 & 255) << 16) | ((unsigned)(q3 & 255) << 24);
}

// blocks [0,1024): one wave per x row -> per-row absmax quantize to i8.
// blocks [1024,2048): grid-stride absmax over codebook -> pmax[bid-1024]
// (plain store; cb_quant reduces the partials -> no atomic, no memset).
__global__ __launch_bounds__(512) void prep(
    const float* __restrict__ x, const float* __restrict__ cb,
    signed char* __restrict__ xq, float* __restrict__ pmax) {
  __shared__ float sm[8];
  if (blockIdx.x < 1024) {
    const int wv = threadIdx.x >> 6, lane = threadIdx.x & 63;
    const int row = blockIdx.x * 8 + wv;
    const float* xr = x + (size_t)row * DIM + lane * 8;
    const float4 v0 = *(const float4*)xr;
    const float4 v1 = *(const float4*)(xr + 4);
    float m = fmaxf(absmax4(v0), absmax4(v1));
#pragma unroll
    for (int d = 1; d < 64; d <<= 1) m = fmaxf(m, __shfl_xor(m, d));
    const float inv = m > 0.f ? 127.0f / m : 0.f;
    uint2 u;
    u.x = pack4(v0.x, v0.y, v0.z, v0.w, inv);
    u.y = pack4(v1.x, v1.y, v1.z, v1.w, inv);
    ((uint2*)(xq + (size_t)row * DIMB))[lane] = u;
  } else {
    const int n4 = K_CODES * DIM / 4;
    float m = 0.f;
    for (int i = (blockIdx.x - 1024) * 512 + threadIdx.x; i < n4; i += 512 * 1024)
      m = fmaxf(m, absmax4(((const float4*)cb)[i]));
#pragma unroll
    for (int d = 1; d < 64; d <<= 1) m = fmaxf(m, __shfl_xor(m, d));
    if ((threadIdx.x & 63) == 0) sm[threadIdx.x >> 6] = m;
    __syncthreads();
    if (threadIdx.x == 0) {
#pragma unroll
      for (int i = 1; i < 8; ++i) m = fmaxf(m, sm[i]);
      pmax[blockIdx.x - 1024] = m;
    }
  }
}

__global__ __launch_bounds__(256) void cb_quant(
    const float* __restrict__ cb, signed char* __restrict__ cq,
    const float* __restrict__ pmax) {
  __shared__ float sm[4];
  float m = 0.f;
#pragma unroll
  for (int q = 0; q < 4; ++q) m = fmaxf(m, pmax[q * 256 + threadIdx.x]);
#pragma unroll
  for (int d = 1; d < 64; d <<= 1) m = fmaxf(m, __shfl_xor(m, d));
  if ((threadIdx.x & 63) == 0) sm[threadIdx.x >> 6] = m;
  __syncthreads();
  const float mx = fmaxf(fmaxf(sm[0], sm[1]), fmaxf(sm[2], sm[3]));
  const float inv = mx > 0.f ? 127.0f / mx : 0.f;
  const size_t t = (size_t)blockIdx.x * 256 + threadIdx.x;  // 8 elems/thread
  const float* src = cb + t * 8;
  const float4 v0 = *(const float4*)src;
  const float4 v1 = *(const float4*)(src + 4);
  uint2 u;
  u.x = pack4(v0.x, v0.y, v0.z, v0.w, inv);
  u.y = pack4(v1.x, v1.y, v1.z, v1.w, inv);
  ((uint2*)cq)[t] = u;
}

__global__ __launch_bounds__(512, 2) void vq_argmax(
    const signed char* __restrict__ xq, const signed char* __restrict__ cq,
    float* __restrict__ pv, int* __restrict__ pi) {
  // 2 rotating single-K-tile buffers x {A,B} x (256 rows x 64B) = 64 KiB
  __shared__ signed char lds[2][2][BM * BKB];

  const int tid = threadIdx.x;
  const int lane = tid & 63;
  const int w = tid >> 6;
  const int wm = w >> 1, wn = w & 1;       // 4M x 2N wave grid
  const int l15 = lane & 15, quad = lane >> 4;
  // swizzled 16B-chunk byte offset for this lane's fragment reads
  const int kq = ((quad ^ ((l15 >> 1) & 3)) << 4);
  const int aoff = (wm * 64 + l15) * BKB + kq;
  const int boff = (wn * 128 + l15) * BKB + kq;

  // staging: slot s = r*512+tid holds logical chunk (row=s>>2, kc=(s&3)^((row>>1)&3))
  int eoff0, eoff1, doff0, doff1;
  {
    const int s1 = 512 + tid;
    const int r0 = tid >> 2, r1 = s1 >> 2;
    eoff0 = r0 * DIMB + (((tid & 3) ^ ((r0 >> 1) & 3)) << 4);
    eoff1 = r1 * DIMB + (((s1 & 3) ^ ((r1 >> 1) & 3)) << 4);
    doff0 = (tid & 448) << 4;
    doff1 = (512 + (tid & 448)) << 4;
  }

  // 2 (rb,split) units per block: 256 blocks x 2 = 512 units
#pragma unroll 1
  for (int u = 0; u < 2; ++u) {
    const int unit = u * 256 + blockIdx.x;
    const int rb = unit & 31;
    const int split = unit >> 5;
    const int row0 = rb * BM;
    const signed char* Asrc = xq + (size_t)row0 * DIMB;
    const signed char* Bsrc = cq + (size_t)split * (K_CODES / NSPLIT) * DIMB;

    auto stageA = [&](int t) {
      const signed char* g = Asrc + (t & 7) * BKB;
      signed char* l = &lds[t & 1][0][0];
      gll16(g + eoff0, l + doff0);
      gll16(g + eoff1, l + doff1);
    };
    auto stageB = [&](int t) {
      const signed char* g = Bsrc + (size_t)(t >> 3) * (BN * DIMB) + (t & 7) * BKB;
      signed char* l = &lds[t & 1][1][0];
      gll16(g + eoff0, l + doff0);
      gll16(g + eoff1, l + doff1);
    };

    // packed top-2 int keys per (i,r) row-slot: key = (D<<5) | icode_inv
    int K1[4][4], K2[4][4];
#pragma unroll
    for (int i = 0; i < 4; ++i)
#pragma unroll
      for (int r = 0; r < 4; ++r) { K1[i][r] = INT_MIN_K; K2[i][r] = INT_MIN_K; }

    i32x4 acc[4][8];

    // tournament fold over one j-half (4 columns): top-2-of-4 via pairwise
    // max/min tree, then top2-union merge into (K1,K2). Keys unique (codes)
    // -> no ties -> branchless network exact.
    auto fold = [&](int j0, int kt) {
      const int icb = 31 - (kt >> 3) * 8;   // icode_inv = icb - j
#pragma unroll
      for (int i = 0; i < 4; ++i)
#pragma unroll
        for (int r = 0; r < 4; ++r) {
          const int k0 = (int)(((unsigned)acc[i][j0 + 0][r] << 5) | (unsigned)(icb - j0 - 0));
          const int k1 = (int)(((unsigned)acc[i][j0 + 1][r] << 5) | (unsigned)(icb - j0 - 1));
          const int k2 = (int)(((unsigned)acc[i][j0 + 2][r] << 5) | (unsigned)(icb - j0 - 2));
          const int k3 = (int)(((unsigned)acc[i][j0 + 3][r] << 5) | (unsigned)(icb - j0 - 3));
          const int h01 = k0 > k1 ? k0 : k1, l01 = k0 > k1 ? k1 : k0;
          const int h23 = k2 > k3 ? k2 : k3, l23 = k2 > k3 ? k3 : k2;
          const int m1 = h01 > h23 ? h01 : h23;
          const int lw = h01 > h23 ? l01 : l23;   // lo of winning pair
          const int lo2 = h01 > h23 ? h23 : h01;  // losing pair's hi
          const int m2 = lw > lo2 ? lw : lo2;     // second of the 4
          // merge top2{K1,K2} with top2{m1,m2}
          const int s = K1[i][r] > m1 ? m1 : K1[i][r];
          const int other = K1[i][r] > m1 ? K2[i][r] : m2;
          K1[i][r] = K1[i][r] > m1 ? K1[i][r] : m1;
          K2[i][r] = s > other ? s : other;
        }
    };

    // prologue: stage K-tile 0, drain, sync (also the unit seam barrier)
    stageA(0); stageB(0);
    asm volatile("s_waitcnt vmcnt(0)" ::: "memory");
    __builtin_amdgcn_s_barrier();
    asm volatile("" ::: "memory");

#pragma unroll 1
    for (int kt = 0; kt < G; ++kt) {
      const int bk = kt & 1;
      // stage kt+1 FIRST (max in-flight time before the end-of-tile drain)
      if (kt + 1 < G) { stageA(kt + 1); stageB(kt + 1); }

      if ((kt & 7) == 0) {
#pragma unroll
        for (int i = 0; i < 4; ++i)
#pragma unroll
          for (int j = 0; j < 8; ++j) acc[i][j] = (i32x4){0, 0, 0, 0};
      }
      const signed char* Ab = &lds[bk][0][0];
      const signed char* Bb = &lds[bk][1][0];

      // all 12 fragment reads up front in need-order; counted lgkm lets the
      // later B reads complete under the first MFMA group
      i32x4 A_[4], B_[8];
#pragma unroll
      for (int i = 0; i < 4; ++i) A_[i] = *(const i32x4*)&Ab[aoff + i * (16 * BKB)];
#pragma unroll
      for (int j = 0; j < 8; ++j) B_[j] = *(const i32x4*)&Bb[boff + j * (16 * BKB)];

      __builtin_amdgcn_s_setprio(1);
#pragma unroll
      for (int j = 0; j < 4; ++j)
#pragma unroll
        for (int i = 0; i < 4; ++i)
          acc[i][j] = __builtin_amdgcn_mfma_i32_16x16x64_i8(A_[i], B_[j], acc[i][j], 0, 0, 0);
      __builtin_amdgcn_s_setprio(0);
      if ((kt & 7) == 7) fold(0, kt);   // VALU half-fold under next MFMA group
      __builtin_amdgcn_s_setprio(1);
#pragma unroll
      for (int j = 4; j < 8; ++j)
#pragma unroll
        for (int i = 0; i < 4; ++i)
          acc[i][j] = __builtin_amdgcn_mfma_i32_16x16x64_i8(A_[i], B_[j], acc[i][j], 0, 0, 0);
      __builtin_amdgcn_s_setprio(0);
      if ((kt & 7) == 7) fold(4, kt);

      // drain this wave's kt+1 stages, then globalize
      if (kt + 1 < G) {
        asm volatile("s_waitcnt vmcnt(0)" ::: "memory");
        __builtin_amdgcn_s_barrier();
        asm volatile("" ::: "memory");
      }
    }

    // butterfly-merge top-2 across the 16 column-lanes of each quad, recover
    // winner lane via ballot (first set bit = lowest l15 = lowest index on tie)
    const int nb = split * (K_CODES / NSPLIT);
#pragma unroll
    for (int i = 0; i < 4; ++i)
#pragma unroll
      for (int r = 0; r < 4; ++r) {
        const int p1 = K1[i][r], p2 = K2[i][r];
        int a1 = p1, a2 = p2;
#pragma unroll
        for (int d = 1; d < 16; d <<= 1) {
          const int b1 = __shfl_xor(a1, d);
          const int b2 = __shfl_xor(a2, d);
          const int hi = a1 > b1 ? a1 : b1;
          const int lo = a1 > b1 ? b1 : a1;
          const int mx = a2 > b2 ? a2 : b2;
          a1 = hi;
          a2 = lo > mx ? lo : mx;
        }
        const unsigned long long bl1 = __ballot(p1 == a1);
        const int s1 = __ffsll((unsigned long long)((bl1 >> (quad * 16)) & 0xFFFFull)) - 1;
        const unsigned long long bl2 = __ballot((p2 == a2) || (p1 == a2 && l15 != s1));
        const int s2 = __ffsll((unsigned long long)((bl2 >> (quad * 16)) & 0xFFFFull)) - 1;
        if (l15 == 0) {
          const int code1 = 31 - (a1 & 31);
          const int code2 = 31 - (a2 & 31);
          const int col1 = nb + (code1 >> 3) * BN + wn * 128 + (code1 & 7) * 16 + s1;
          const int col2 = nb + (code2 >> 3) * BN + wn * 128 + (code2 & 7) * 16 + s2;
          const int rl = wm * 64 + i * 16 + quad * 4 + r;
          const size_t o = (size_t)(row0 + rl) * 64 + (size_t)(split * 4 + wn * 2);
          pv[o] = (float)(a1 >> 5); pi[o] = col1;       // D in int units; margin
          pv[o + 1] = (float)(a2 >> 5); pi[o + 1] = col2;  // test is relative/row
        }
      }
  }
}

__global__ void recheck_gather(const float* __restrict__ pv, const int* __restrict__ pi,
                               const float* __restrict__ x, const float* __restrict__ cb,
                               float* __restrict__ out) {
  const int row = blockIdx.x;
  const int lane = threadIdx.x;   // 64 candidates = 16 splits x 2 halves x top-2
  float v = pv[(size_t)row * 64 + lane];
  int ci = pi[(size_t)row * 64 + lane];

  // wave max with lowest-index tie-break
  float m1 = v; int mi1 = ci;
#pragma unroll
  for (int d = 1; d < 64; d <<= 1) {
    float ov = __shfl_xor(m1, d);
    int oi = __shfl_xor(mi1, d);
    if (ov > m1 || (ov == m1 && oi < mi1)) { m1 = ov; mi1 = oi; }
  }

  const bool flag = (v >= m1 - MARGIN_I);
  const unsigned long long mask = __ballot(flag);
  int winner;
  if (__popcll(mask) == 1) {
    winner = mi1;   // approx winner is ~29-sigma clear of every other candidate
  } else {
    // exact fp64 dot from original fp32 inputs for each flagged candidate
    double e = -1.0e300;
    if (flag) {
      const float* xr = x + (size_t)row * DIM;
      const float* cr = cb + (size_t)ci * DIM;
      double s = 0.0;
#pragma unroll 4
      for (int t = 0; t < DIM; t += 4) {
        const float4 a = *(const float4*)(xr + t);
        const float4 b = *(const float4*)(cr + t);
        s += (double)a.x * b.x + (double)a.y * b.y + (double)a.z * b.z + (double)a.w * b.w;
      }
      e = s;
    }
    int ei = flag ? ci : 0x7fffffff;
#pragma unroll
    for (int d = 1; d < 64; d <<= 1) {
      double oe = __shfl_xor(e, d);
      int oi = __shfl_xor(ei, d);
      if (oe > e || (oe == e && oi < ei)) { e = oe; ei = oi; }
    }
    winner = ei;
  }

  const float4* src = (const float4*)(cb + (size_t)winner * DIM);
  float4* dst = (float4*)(out + (size_t)row * DIM);
  dst[lane] = src[lane];         // 512 f32 = 128 float4, 64 lanes x 2
  dst[lane + 64] = src[lane + 64];
}

extern "C" void kernel_launch(void* const* d_in, const int* in_sizes, int n_in,
                              void* d_out, int out_size, void* d_ws, size_t ws_size,
                              hipStream_t stream) {
  const float* x = (const float*)d_in[0];
  const float* cb = (const float*)d_in[1];
  float* out = (float*)d_out;

  // ws layout: xq(4MB) cq(8MB) pv(2MB) pi(2MB) pmax(4KB)
  signed char* xq = (signed char*)d_ws;
  signed char* cq = xq + (size_t)M_ROWS * DIMB;
  float* pv = (float*)(cq + (size_t)K_CODES * DIMB);
  int* pi = (int*)(pv + (size_t)M_ROWS * 64);
  float* pmax = (float*)(pi + (size_t)M_ROWS * 64);

  prep<<<2048, 512, 0, stream>>>(x, cb, xq, pmax);
  cb_quant<<<K_CODES * DIM / 8 / 256, 256, 0, stream>>>(cb, cq, pmax);
  vq_argmax<<<256, 512, 0, stream>>>(xq, cq, pv, pi);
  recheck_gather<<<M_ROWS, 64, 0, stream>>>(pv, pi, x, cb, out);
}